// Round 6
// baseline (127.524 us; speedup 1.0000x reference)
//
#include <hip/hip_runtime.h>
#include <stdint.h>

#define N_ROWS 8192
#define DIM 128
#define BM 128
#define NCLS 100
#define NPAIRS 2080       // 64*65/2 upper-triangular 128x128 tile pairs
#define CS_SLOTS 32
#define CS_BLOCKS (CS_SLOTS * NCLS)   // 3200 class-sum blocks

typedef short bf16x8 __attribute__((ext_vector_type(8)));
typedef float f32x4 __attribute__((ext_vector_type(4)));

template <bool B> struct BoolC { static constexpr bool value = B; };

__device__ __forceinline__ unsigned f2bf(float x) {
  union { float f; unsigned u; } c; c.f = x;
  return (c.u + 0x7FFFu + ((c.u >> 16) & 1u)) >> 16;  // RNE to bf16
}
__device__ __forceinline__ float bf2f(unsigned u) {
  union { unsigned u; float f; } c; c.u = u << 16; return c.f;
}

// Kernel 1: L2-normalize rows fp32 -> bf16 (Abf); zero Z; blocks 0..50 also
// zero G (100*128 f32) + hist (100 i32), which sit contiguous in ws.
__global__ __launch_bounds__(256) void normalize_kernel(
    const float* __restrict__ F, unsigned short* __restrict__ Abf,
    float* __restrict__ Z, float* __restrict__ G) {
  const int tid = threadIdx.x, wave = tid >> 6, lane = tid & 63;
  const int b = blockIdx.x;
  if (b < 51) {
    int zi = b * 256 + tid;
    if (zi < NCLS * DIM + NCLS) G[zi] = 0.f;  // covers G then hist (bit-zero)
  }
  const int row = b * 4 + wave;
  float2 v = ((const float2*)(F + (size_t)row * DIM))[lane];
  float ss = v.x * v.x + v.y * v.y;
  #pragma unroll
  for (int m = 1; m < 64; m <<= 1) ss += __shfl_xor(ss, m, 64);
  float scale = rsqrtf(fmaxf(ss, 1e-24f));
  unsigned bx = f2bf(v.x * scale), by = f2bf(v.y * scale);
  ((unsigned*)Abf)[(size_t)row * (DIM / 2) + lane] = bx | (by << 16);
  if (lane == 0) Z[row] = 0.f;
}

// Kernel 2 (mega): blocks [0,CS_BLOCKS) = class-sum (slot s scans 256 rows,
// ~1-deep gather chains, atomics to G/hist). Blocks [CS_BLOCKS, +NPAIRS) =
// symmetric-Z tile pairs. 4 blocks/CU (16 waves/CU): the kernel is
// latency-bound, occupancy is the lever (R5: 2 blocks/CU -> 24.7% occ).
__global__ __launch_bounds__(256, 4) void mega_kernel(
    const unsigned short* __restrict__ Abf, const int* __restrict__ L,
    float* __restrict__ Z, float* __restrict__ G, int* __restrict__ hist,
    float* __restrict__ out) {
  __shared__ __align__(16) unsigned short sB[BM * DIM];  // 32 KB
  __shared__ float sred[256];  // scl: row/col partials ; csum: scnt alias

  const int tid = threadIdx.x, lane = tid & 63, wave = tid >> 6;
  const int b = blockIdx.x;

  if (b < CS_BLOCKS) {
    // ---- class-sum branch ----
    const int s = b / NCLS, c = b % NCLS;
    if (b == 0 && tid == 0) out[0] = 0.f;  // before finalize in stream order
    const int base = s * 256 + wave * 64;
    int lab = L[base + lane];
    unsigned long long m = __ballot(lab == c);
    int cnt = (int)__popcll(m);
    float gx = 0.f, gy = 0.f;
    while (m) {
      int j = __ffsll((long long)m) - 1; m &= m - 1;
      unsigned pk = ((const unsigned*)(Abf + (size_t)(base + j) * DIM))[lane];
      gx += bf2f(pk & 0xffffu); gy += bf2f(pk >> 16);
    }
    float* sg = (float*)sB;
    int* scnt = (int*)sred;
    sg[wave * DIM + lane * 2] = gx; sg[wave * DIM + lane * 2 + 1] = gy;
    if (lane == 0) scnt[wave] = cnt;
    __syncthreads();
    if (wave == 0) {
      int ct = scnt[0] + scnt[1] + scnt[2] + scnt[3];
      if (ct > 0) {
        float a = sg[0 * DIM + lane * 2] + sg[1 * DIM + lane * 2] +
                  sg[2 * DIM + lane * 2] + sg[3 * DIM + lane * 2];
        float d = sg[0 * DIM + lane * 2 + 1] + sg[1 * DIM + lane * 2 + 1] +
                  sg[2 * DIM + lane * 2 + 1] + sg[3 * DIM + lane * 2 + 1];
        atomicAdd(&G[(size_t)c * DIM + lane * 2], a);
        atomicAdd(&G[(size_t)c * DIM + lane * 2 + 1], d);
        if (lane == 0) atomicAdd(&hist[c], ct);
      }
    }
    return;
  }

  // ---- symmetric-Z tile branch ----
  const int wi = wave >> 1, wj = wave & 1;
  const int quad = lane >> 4, l15 = lane & 15;

  // triangular decode: t -> (bi, bj); off(bi) = bi*(129-bi)/2
  const int t = b - CS_BLOCKS;
  int bi = (int)((129.0f - sqrtf(16641.0f - 8.0f * (float)t)) * 0.5f);
  if (bi < 0) bi = 0; if (bi > 63) bi = 63;
  while (bi * (129 - bi) / 2 > t) --bi;
  while ((bi + 1) * (128 - bi) / 2 <= t) ++bi;
  const int bj = bi + (t - bi * (129 - bi) / 2);
  const int i0 = bi * BM, j0 = bj * BM;
  const bool diag = (bi == bj);

  // A fragments first (their latency overlaps the B stage; one vmcnt drain)
  bf16x8 af[4][4];  // [ti][ks]
  #pragma unroll
  for (int ti = 0; ti < 4; ++ti)
    #pragma unroll
    for (int ks = 0; ks < 4; ++ks)
      af[ti][ks] = *(const bf16x8*)(Abf +
          (size_t)(i0 + wi * 64 + ti * 16 + l15) * DIM + ks * 32 + quad * 8);

  // stage B tile: linear LDS dest, inverse-swizzled global source.
  // physical chunk c of row r holds logical chunk (c ^ (r&7)).
  #pragma unroll
  for (int k = 0; k < 8; ++k) {
    int idx = tid + k * 256;
    int r = idx >> 4, cch = idx & 15;
    int sch = cch ^ (r & 7);
    const unsigned short* src = Abf + (size_t)(j0 + r) * DIM + sch * 8;
    unsigned short* dst = sB + (size_t)(k * 256 + (tid & ~63)) * 8;
    __builtin_amdgcn_global_load_lds(
        (const __attribute__((address_space(1))) unsigned int*)src,
        (__attribute__((address_space(3))) unsigned int*)dst, 16, 0, 0);
  }

  __syncthreads();  // vmcnt drain + barrier: sB visible, af in regs

  f32x4 acc[4][4];
  #pragma unroll
  for (int a = 0; a < 4; ++a)
    #pragma unroll
    for (int bq = 0; bq < 4; ++bq)
      acc[a][bq] = (f32x4){0.f, 0.f, 0.f, 0.f};

  #pragma unroll
  for (int ks = 0; ks < 4; ++ks) {
    bf16x8 bfr[4];
    const int kc = ks * 4 + quad;
    #pragma unroll
    for (int tj = 0; tj < 4; ++tj) {
      const int rB = wj * 64 + tj * 16 + l15;
      bfr[tj] = *(const bf16x8*)&sB[(size_t)rB * DIM + ((kc ^ (rB & 7)) * 8)];
    }
    #pragma unroll
    for (int ti = 0; ti < 4; ++ti)
      #pragma unroll
      for (int tj = 0; tj < 4; ++tj)
        acc[ti][tj] = __builtin_amdgcn_mfma_f32_16x16x32_bf16(
            af[ti][ks], bfr[tj], acc[ti][tj], 0, 0, 0);
  }

  const float K1 = 20.6099291555566280f;  // log2(e)/0.07 ; tt = c*K1 - K1
  float zrow[16];
  float zcol[4] = {0.f, 0.f, 0.f, 0.f};

  auto epi = [&](auto DIAG) {
    #pragma unroll
    for (int ti = 0; ti < 4; ++ti) {
      #pragma unroll
      for (int rg = 0; rg < 4; ++rg) {
        float z = 0.f;
        #pragma unroll
        for (int tj = 0; tj < 4; ++tj) {
          float cv = acc[ti][tj][rg];
          float tt = fmaf(cv, K1, -K1);
          float e = exp2f(tt);
          if constexpr (decltype(DIAG)::value) {
            int tr = wi * 64 + ti * 16 + quad * 4 + rg;
            int tc = wj * 64 + tj * 16 + l15;
            e = (tr != tc) ? e : 0.f;
          }
          z += e;
          zcol[tj] += e;
        }
        zrow[ti * 4 + rg] = z;
      }
    }
  };
  if (diag) epi(BoolC<true>{}); else epi(BoolC<false>{});

  // row reduce across the 16 column-lanes (valid at l15==0)
  #pragma unroll
  for (int q = 0; q < 16; ++q) {
    float z = zrow[q];
    #pragma unroll
    for (int m = 1; m < 16; m <<= 1) z += __shfl_xor(z, m, 64);
    zrow[q] = z;
  }
  // col reduce across the 4 quads (valid at quad==0)
  #pragma unroll
  for (int tj = 0; tj < 4; ++tj) {
    float zc = zcol[tj];
    zc += __shfl_xor(zc, 16, 64);
    zc += __shfl_xor(zc, 32, 64);
    zcol[tj] = zc;
  }

  // sred is dedicated (not aliasing sB) -> no barrier needed before writes
  if (wj == 0) {
    #pragma unroll
    for (int q = 0; q < 16; ++q)
      if (l15 == 0) sred[wi * 64 + (q >> 2) * 16 + quad * 4 + (q & 3)] = zrow[q];
  }
  if (!diag && wi == 0 && quad == 0) {
    #pragma unroll
    for (int tj = 0; tj < 4; ++tj)
      sred[128 + wj * 64 + tj * 16 + l15] = zcol[tj];
  }
  __syncthreads();
  if (wj == 1) {
    #pragma unroll
    for (int q = 0; q < 16; ++q)
      if (l15 == 0) {
        int r = wi * 64 + (q >> 2) * 16 + quad * 4 + (q & 3);
        atomicAdd(&Z[i0 + r], zrow[q] + sred[r]);
      }
  }
  if (!diag && wi == 1 && quad == 0) {
    #pragma unroll
    for (int tj = 0; tj < 4; ++tj) {
      int cc = wj * 64 + tj * 16 + l15;
      atomicAdd(&Z[j0 + cc], zcol[tj] + sred[128 + cc]);
    }
  }
}

// Kernel 3: per-row loss. One wave per row:
//   P = hist[c]-1 ;  sum_pos sim = dot(f_i, G[c]) - dot(f_i, f_i)
//   lp = ((sumpos - P)/T)/P - log(Z + 1e-12) ;  out = -mean(lp)
__global__ __launch_bounds__(256) void finalize_kernel(
    const unsigned short* __restrict__ Abf, const int* __restrict__ L,
    const float* __restrict__ Z, const float* __restrict__ G,
    const int* __restrict__ hist, float* __restrict__ out) {
  __shared__ float red[4];
  const int wave = threadIdx.x >> 6, lane = threadIdx.x & 63;
  const int row = blockIdx.x * 4 + wave;
  unsigned pk = ((const unsigned*)(Abf + (size_t)row * DIM))[lane];
  float fx = bf2f(pk & 0xffffu), fy = bf2f(pk >> 16);
  int c = L[row];
  float gx = G[(size_t)c * DIM + lane * 2];
  float gy = G[(size_t)c * DIM + lane * 2 + 1];
  float dg = fx * gx + fy * gy;
  float ds = fx * fx + fy * fy;
  #pragma unroll
  for (int m = 1; m < 64; m <<= 1) {
    dg += __shfl_xor(dg, m, 64);
    ds += __shfl_xor(ds, m, 64);
  }
  if (lane == 0) {
    float P = (float)(hist[c] - 1);
    float ssum = ((dg - ds) - P) * (1.0f / 0.07f);
    red[wave] = ssum / P - logf(Z[row] + 1e-12f);
  }
  __syncthreads();
  if (threadIdx.x == 0) {
    float s = red[0] + red[1] + red[2] + red[3];
    atomicAdd(out, -s * (1.0f / (float)N_ROWS));
  }
}

extern "C" void kernel_launch(void* const* d_in, const int* in_sizes, int n_in,
                              void* d_out, int out_size, void* d_ws, size_t ws_size,
                              hipStream_t stream) {
  const float* F = (const float*)d_in[0];
  const int* L = (const int*)d_in[1];
  unsigned short* Abf = (unsigned short*)d_ws;                      // 2 MB
  float* Z = (float*)((char*)d_ws + (size_t)N_ROWS * DIM * 2);      // 32 KB
  float* G = Z + N_ROWS;                                            // 100*128 f32
  int* hist = (int*)(G + (size_t)NCLS * DIM);                       // 400 B (right after G)
  float* out = (float*)d_out;

  normalize_kernel<<<N_ROWS / 4, 256, 0, stream>>>(F, Abf, Z, G);
  mega_kernel<<<CS_BLOCKS + NPAIRS, 256, 0, stream>>>(Abf, L, Z, G, hist, out);
  finalize_kernel<<<N_ROWS / 4, 256, 0, stream>>>(Abf, L, Z, G, hist, out);
}

// Round 7
// 117.182 us; speedup vs baseline: 1.0882x; 1.0882x over previous
//
#include <hip/hip_runtime.h>
#include <stdint.h>

#define N_ROWS 8192
#define DIM 128
#define BM 128
#define NCLS 100
#define NBT 64                      // 128-row tile blocks
#define NPAIRS 2080                 // 64*65/2 upper-triangular tile pairs
#define NSLOT 8
#define CS_BLOCKS (NSLOT * NCLS)    // 800 class-sum blocks

typedef short bf16x8 __attribute__((ext_vector_type(8)));
typedef float f32x4 __attribute__((ext_vector_type(4)));

template <bool B> struct BoolC { static constexpr bool value = B; };

__device__ __forceinline__ unsigned f2bf(float x) {
  union { float f; unsigned u; } c; c.f = x;
  return (c.u + 0x7FFFu + ((c.u >> 16) & 1u)) >> 16;  // RNE to bf16
}
__device__ __forceinline__ float bf2f(unsigned u) {
  union { unsigned u; float f; } c; c.u = u << 16; return c.f;
}

// Kernel 1: L2-normalize rows fp32 -> bf16 (Abf). Nothing else (all later
// reductions are write-exact partials -> no zero-init of anything needed).
__global__ __launch_bounds__(256) void normalize_kernel(
    const float* __restrict__ F, unsigned short* __restrict__ Abf) {
  const int wave = threadIdx.x >> 6, lane = threadIdx.x & 63;
  const int row = blockIdx.x * 4 + wave;
  float2 v = ((const float2*)(F + (size_t)row * DIM))[lane];
  float ss = v.x * v.x + v.y * v.y;
  #pragma unroll
  for (int m = 1; m < 64; m <<= 1) ss += __shfl_xor(ss, m, 64);
  float scale = rsqrtf(fmaxf(ss, 1e-24f));
  unsigned bx = f2bf(v.x * scale), by = f2bf(v.y * scale);
  ((unsigned*)Abf)[(size_t)row * (DIM / 2) + lane] = bx | (by << 16);
}

// Kernel 2 (mega): blocks [0,NPAIRS) = symmetric-Z tile pairs writing
// EXCLUSIVE partial slots Zp[o][row] with plain coalesced stores (zero
// atomics).  Blocks [NPAIRS, +CS_BLOCKS) = class-sum slot partials
// (plain stores to G4[s]/hist4[s], zero atomics).
__global__ __launch_bounds__(256, 4) void mega_kernel(
    const unsigned short* __restrict__ Abf, const int* __restrict__ L,
    float* __restrict__ Zp, float* __restrict__ G4, int* __restrict__ hist4,
    float* __restrict__ out) {
  __shared__ __align__(16) unsigned short sB[BM * DIM];  // 32 KB
  __shared__ float sred[256];  // tile: row/col partials ; csum: scnt alias

  const int tid = threadIdx.x, lane = tid & 63, wave = tid >> 6;
  const int b = blockIdx.x;

  if (b >= NPAIRS) {
    // ---- class-sum branch: slot s scans 1024 rows, plain stores ----
    const int bc = b - NPAIRS;
    const int s = bc / NCLS, c = bc % NCLS;
    const int base = s * 1024 + wave * 256;
    int labs[4];
    #pragma unroll
    for (int it = 0; it < 4; ++it) labs[it] = L[base + it * 64 + lane];
    float gx = 0.f, gy = 0.f;
    int cnt = 0;
    #pragma unroll
    for (int it = 0; it < 4; ++it) {
      unsigned long long m = __ballot(labs[it] == c);
      cnt += (int)__popcll(m);
      const int r0 = base + it * 64;
      while (m) {
        int j = __ffsll((long long)m) - 1; m &= m - 1;
        unsigned pk = ((const unsigned*)(Abf + (size_t)(r0 + j) * DIM))[lane];
        gx += bf2f(pk & 0xffffu); gy += bf2f(pk >> 16);
      }
    }
    float* sg = (float*)sB;
    int* scnt = (int*)sred;
    sg[wave * DIM + lane * 2] = gx; sg[wave * DIM + lane * 2 + 1] = gy;
    if (lane == 0) scnt[wave] = cnt;
    __syncthreads();
    if (wave == 0) {
      float a = sg[0 * DIM + lane * 2] + sg[1 * DIM + lane * 2] +
                sg[2 * DIM + lane * 2] + sg[3 * DIM + lane * 2];
      float d = sg[0 * DIM + lane * 2 + 1] + sg[1 * DIM + lane * 2 + 1] +
                sg[2 * DIM + lane * 2 + 1] + sg[3 * DIM + lane * 2 + 1];
      float* g = G4 + ((size_t)s * NCLS + c) * DIM;
      g[lane * 2] = a; g[lane * 2 + 1] = d;
      if (lane == 0) hist4[s * NCLS + c] = scnt[0] + scnt[1] + scnt[2] + scnt[3];
    }
    return;
  }

  // ---- symmetric-Z tile branch ----
  if (b == 0 && tid == 0) out[0] = 0.f;  // stream-ordered before finalize
  const int wi = wave >> 1, wj = wave & 1;
  const int quad = lane >> 4, l15 = lane & 15;

  // triangular decode: t -> (bi, bj); off(bi) = bi*(129-bi)/2
  const int t = b;
  int bi = (int)((129.0f - sqrtf(16641.0f - 8.0f * (float)t)) * 0.5f);
  if (bi < 0) bi = 0; if (bi > 63) bi = 63;
  while (bi * (129 - bi) / 2 > t) --bi;
  while ((bi + 1) * (128 - bi) / 2 <= t) ++bi;
  const int bj = bi + (t - bi * (129 - bi) / 2);
  const int i0 = bi * BM, j0 = bj * BM;
  const bool diag = (bi == bj);

  // A fragments first (their latency overlaps the B stage; one vmcnt drain)
  bf16x8 af[4][4];  // [ti][ks]
  #pragma unroll
  for (int ti = 0; ti < 4; ++ti)
    #pragma unroll
    for (int ks = 0; ks < 4; ++ks)
      af[ti][ks] = *(const bf16x8*)(Abf +
          (size_t)(i0 + wi * 64 + ti * 16 + l15) * DIM + ks * 32 + quad * 8);

  // stage B tile: linear LDS dest, inverse-swizzled global source.
  // physical chunk c of row r holds logical chunk (c ^ (r&7)).
  #pragma unroll
  for (int k = 0; k < 8; ++k) {
    int idx = tid + k * 256;
    int r = idx >> 4, cch = idx & 15;
    int sch = cch ^ (r & 7);
    const unsigned short* src = Abf + (size_t)(j0 + r) * DIM + sch * 8;
    unsigned short* dst = sB + (size_t)(k * 256 + (tid & ~63)) * 8;
    __builtin_amdgcn_global_load_lds(
        (const __attribute__((address_space(1))) unsigned int*)src,
        (__attribute__((address_space(3))) unsigned int*)dst, 16, 0, 0);
  }

  __syncthreads();  // vmcnt drain + barrier: sB visible, af in regs

  f32x4 acc[4][4];
  #pragma unroll
  for (int a = 0; a < 4; ++a)
    #pragma unroll
    for (int bq = 0; bq < 4; ++bq)
      acc[a][bq] = (f32x4){0.f, 0.f, 0.f, 0.f};

  #pragma unroll
  for (int ks = 0; ks < 4; ++ks) {
    bf16x8 bfr[4];
    const int kc = ks * 4 + quad;
    #pragma unroll
    for (int tj = 0; tj < 4; ++tj) {
      const int rB = wj * 64 + tj * 16 + l15;
      bfr[tj] = *(const bf16x8*)&sB[(size_t)rB * DIM + ((kc ^ (rB & 7)) * 8)];
    }
    #pragma unroll
    for (int ti = 0; ti < 4; ++ti)
      #pragma unroll
      for (int tj = 0; tj < 4; ++tj)
        acc[ti][tj] = __builtin_amdgcn_mfma_f32_16x16x32_bf16(
            af[ti][ks], bfr[tj], acc[ti][tj], 0, 0, 0);
  }

  const float K1 = 20.6099291555566280f;  // log2(e)/0.07 ; tt = c*K1 - K1
  float zrow[16];
  float zcol[4] = {0.f, 0.f, 0.f, 0.f};

  auto epi = [&](auto DIAG) {
    #pragma unroll
    for (int ti = 0; ti < 4; ++ti) {
      #pragma unroll
      for (int rg = 0; rg < 4; ++rg) {
        float z = 0.f;
        #pragma unroll
        for (int tj = 0; tj < 4; ++tj) {
          float cv = acc[ti][tj][rg];
          float tt = fmaf(cv, K1, -K1);
          float e = exp2f(tt);
          if constexpr (decltype(DIAG)::value) {
            int tr = wi * 64 + ti * 16 + quad * 4 + rg;
            int tc = wj * 64 + tj * 16 + l15;
            e = (tr != tc) ? e : 0.f;
          }
          z += e;
          zcol[tj] += e;
        }
        zrow[ti * 4 + rg] = z;
      }
    }
  };
  if (diag) epi(BoolC<true>{}); else epi(BoolC<false>{});

  // row reduce across the 16 column-lanes (valid at l15==0)
  #pragma unroll
  for (int q = 0; q < 16; ++q) {
    float z = zrow[q];
    #pragma unroll
    for (int m = 1; m < 16; m <<= 1) z += __shfl_xor(z, m, 64);
    zrow[q] = z;
  }
  // col reduce across the 4 quads (valid at quad==0)
  #pragma unroll
  for (int tj = 0; tj < 4; ++tj) {
    float zc = zcol[tj];
    zc += __shfl_xor(zc, 16, 64);
    zc += __shfl_xor(zc, 32, 64);
    zcol[tj] = zc;
  }

  // combine the two wave-halves in LDS, then one coalesced store per half.
  if (wj == 0) {
    #pragma unroll
    for (int q = 0; q < 16; ++q)
      if (l15 == 0) sred[wi * 64 + (q >> 2) * 16 + quad * 4 + (q & 3)] = zrow[q];
  }
  if (wi == 0 && quad == 0) {
    #pragma unroll
    for (int tj = 0; tj < 4; ++tj)
      sred[128 + wj * 64 + tj * 16 + l15] = zcol[tj];
  }
  __syncthreads();
  if (wj == 1) {
    #pragma unroll
    for (int q = 0; q < 16; ++q)
      if (l15 == 0) {
        int r = wi * 64 + (q >> 2) * 16 + quad * 4 + (q & 3);
        sred[r] += zrow[q];
      }
  }
  if (wi == 1 && quad == 0) {
    #pragma unroll
    for (int tj = 0; tj < 4; ++tj)
      sred[128 + wj * 64 + tj * 16 + l15] += zcol[tj];
  }
  __syncthreads();
  // exclusive partial slots: rows -> Zp[bj][i0..], cols -> Zp[bi][j0..]
  if (tid < 128) {
    Zp[(size_t)bj * N_ROWS + i0 + tid] = sred[tid];
  } else if (!diag) {
    Zp[(size_t)bi * N_ROWS + j0 + (tid - 128)] = sred[tid];
  }
}

// Kernel 3: per-row loss. One wave per row:
//   Z = sum_o Zp[o][row] ; P = hist[c]-1
//   sum_pos sim = dot(f_i, G[c]) - dot(f_i, f_i)
//   lp = ((sumpos - P)/T)/P - log(Z + 1e-12) ;  out = -mean(lp)
__global__ __launch_bounds__(256) void finalize_kernel(
    const unsigned short* __restrict__ Abf, const int* __restrict__ L,
    const float* __restrict__ Zp, const float* __restrict__ G4,
    const int* __restrict__ hist4, float* __restrict__ out) {
  __shared__ float red[4];
  const int wave = threadIdx.x >> 6, lane = threadIdx.x & 63;
  const int row = blockIdx.x * 4 + wave;
  float zq = Zp[(size_t)lane * N_ROWS + row];
  unsigned pk = ((const unsigned*)(Abf + (size_t)row * DIM))[lane];
  float fx = bf2f(pk & 0xffffu), fy = bf2f(pk >> 16);
  int c = L[row];
  float gx = 0.f, gy = 0.f;
  #pragma unroll
  for (int s = 0; s < NSLOT; ++s) {
    const float* g = G4 + ((size_t)s * NCLS + c) * DIM;
    gx += g[lane * 2]; gy += g[lane * 2 + 1];
  }
  int h = (lane < NSLOT) ? hist4[lane * NCLS + c] : 0;
  float dg = fx * gx + fy * gy;
  float ds = fx * fx + fy * fy;
  #pragma unroll
  for (int m = 1; m < 64; m <<= 1) {
    dg += __shfl_xor(dg, m, 64);
    ds += __shfl_xor(ds, m, 64);
    zq += __shfl_xor(zq, m, 64);
  }
  #pragma unroll
  for (int m = 1; m < 8; m <<= 1) h += __shfl_xor(h, m, 64);
  if (lane == 0) {
    float P = (float)(h - 1);
    float ssum = ((dg - ds) - P) * (1.0f / 0.07f);
    red[wave] = ssum / P - logf(zq + 1e-12f);
  }
  __syncthreads();
  if (threadIdx.x == 0) {
    float s = red[0] + red[1] + red[2] + red[3];
    atomicAdd(out, -s * (1.0f / (float)N_ROWS));
  }
}

extern "C" void kernel_launch(void* const* d_in, const int* in_sizes, int n_in,
                              void* d_out, int out_size, void* d_ws, size_t ws_size,
                              hipStream_t stream) {
  const float* F = (const float*)d_in[0];
  const int* L = (const int*)d_in[1];
  unsigned short* Abf = (unsigned short*)d_ws;                      // 2 MB
  float* Zp = (float*)((char*)d_ws + (size_t)N_ROWS * DIM * 2);     // 64*8192 f32 = 2 MB
  float* G4 = Zp + (size_t)NBT * N_ROWS;                            // 8*100*128 f32
  int* hist4 = (int*)(G4 + (size_t)NSLOT * NCLS * DIM);             // 3.2 KB
  float* out = (float*)d_out;

  normalize_kernel<<<N_ROWS / 4, 256, 0, stream>>>(F, Abf);
  mega_kernel<<<NPAIRS + CS_BLOCKS, 256, 0, stream>>>(Abf, L, Zp, G4, hist4, out);
  finalize_kernel<<<N_ROWS / 4, 256, 0, stream>>>(Abf, L, Zp, G4, hist4, out);
}